// Round 3
// baseline (3321.885 us; speedup 1.0000x reference)
//
#include <hip/hip_runtime.h>

typedef unsigned short u16;
typedef __bf16 bf16x8 __attribute__((ext_vector_type(8)));
typedef float f32x4 __attribute__((ext_vector_type(4)));

static __device__ __forceinline__ float bf2f(u16 u) {
    return __uint_as_float(((unsigned)u) << 16);
}
static __device__ __forceinline__ u16 f2bf(float f) {
    unsigned u = __float_as_uint(f);
    unsigned r = (u + 0x7FFFu + ((u >> 16) & 1u)) >> 16;
    return (u16)r;
}
// monotonic float<->uint encoding for atomicMax-based segment max (0 == -NaN == minimum)
static __device__ __forceinline__ unsigned encf(float f) {
    unsigned u = __float_as_uint(f);
    return (u & 0x80000000u) ? ~u : (u | 0x80000000u);
}
static __device__ __forceinline__ float decf(unsigned e) {
    unsigned u = (e & 0x80000000u) ? (e & 0x7FFFFFFFu) : ~e;
    return __uint_as_float(u);
}

// ---- edge_index word-stride detection: int32-packed (1) vs int64-as-2-words (2)
__global__ void detect_kernel(const int* __restrict__ ei, int* __restrict__ flag) {
    if (blockIdx.x == 0 && threadIdx.x == 0) {
        int zc = 0;
        for (int t = 0; t < 64; ++t) zc += (ei[2 * t + 1] == 0) ? 1 : 0;
        *flag = (zc >= 60) ? 2 : 1;
    }
}
static __device__ __forceinline__ int ld_idx(const int* ei, int pos, int st, int N) {
    int v = ei[(size_t)pos * (size_t)st];
    return v < 0 ? 0 : (v >= N ? N - 1 : v);
}

// ---------------- GEMM: C[M,NC] = A[M,128] @ W[128,NC]
// A: f32 (AF32=true) or bf16. W: f32, converted to register-resident bf16 frags.
// MFMA 16x16x32 bf16. A: A[m=lane&15][k=quad*8+j]; B: B[k=quad*8+j][n=lane&15];
// D: col=lane&15, row=quad*4+reg.
template <int NC, bool AF32, bool OUTF32>
__global__ __launch_bounds__(256) void gemm_k128(const void* __restrict__ Ap,
                                                 const float* __restrict__ W,
                                                 void* __restrict__ Cout, int M) {
    const int lane = threadIdx.x & 63;
    const int quad = lane >> 4;
    const int r = lane & 15;
    const int gw = (blockIdx.x * 256 + threadIdx.x) >> 6;
    const int nw = (gridDim.x * 256) >> 6;

    bf16x8 bf[NC / 16][4];
#pragma unroll
    for (int nt = 0; nt < NC / 16; ++nt)
#pragma unroll
        for (int kk = 0; kk < 4; ++kk) {
            union { bf16x8 v; u16 s[8]; } u;
#pragma unroll
            for (int j = 0; j < 8; ++j)
                u.s[j] = f2bf(W[(size_t)(kk * 32 + quad * 8 + j) * NC + nt * 16 + r]);
            bf[nt][kk] = u.v;
        }

    const int ntiles = (M + 15) >> 4;
    for (int t = gw; t < ntiles; t += nw) {
        const int row0 = t << 4;
        bf16x8 af[4];
        if (AF32) {
            const float* arow = (const float*)Ap + (size_t)(row0 + r) * 128;
#pragma unroll
            for (int kk = 0; kk < 4; ++kk) {
                f32x4 f0 = *reinterpret_cast<const f32x4*>(arow + kk * 32 + quad * 8);
                f32x4 f1 = *reinterpret_cast<const f32x4*>(arow + kk * 32 + quad * 8 + 4);
                union { bf16x8 v; u16 s[8]; } u;
#pragma unroll
                for (int j = 0; j < 4; ++j) { u.s[j] = f2bf(f0[j]); u.s[4 + j] = f2bf(f1[j]); }
                af[kk] = u.v;
            }
        } else {
            const u16* arow = (const u16*)Ap + (size_t)(row0 + r) * 128;
#pragma unroll
            for (int kk = 0; kk < 4; ++kk)
                af[kk] = *reinterpret_cast<const bf16x8*>(arow + kk * 32 + quad * 8);
        }
        f32x4 acc[NC / 16];
#pragma unroll
        for (int nt = 0; nt < NC / 16; ++nt) acc[nt] = (f32x4){0.f, 0.f, 0.f, 0.f};
#pragma unroll
        for (int kk = 0; kk < 4; ++kk)
#pragma unroll
            for (int nt = 0; nt < NC / 16; ++nt)
                acc[nt] = __builtin_amdgcn_mfma_f32_16x16x32_bf16(af[kk], bf[nt][kk],
                                                                  acc[nt], 0, 0, 0);
#pragma unroll
        for (int nt = 0; nt < NC / 16; ++nt)
#pragma unroll
            for (int reg = 0; reg < 4; ++reg) {
                int row = row0 + quad * 4 + reg;
                int col = nt * 16 + r;
                if (OUTF32)
                    ((float*)Cout)[(size_t)row * NC + col] = acc[nt][reg];
                else
                    ((u16*)Cout)[(size_t)row * NC + col] = f2bf(acc[nt][reg]);
            }
    }
}

// ---------------- per-node attention scores s_src = h.a_src, s_dst = h.a_dst
__global__ __launch_bounds__(256) void scores_kernel(const u16* __restrict__ h,
                                                     const float* __restrict__ asrc,
                                                     const float* __restrict__ adst,
                                                     float* __restrict__ ssrc,
                                                     float* __restrict__ sdst, int N) {
    const int lane = threadIdx.x & 63;
    const int gw = (blockIdx.x * 256 + threadIdx.x) >> 6;
    const int nw = (gridDim.x * 256) >> 6;
    const float as0 = asrc[2 * lane], as1 = asrc[2 * lane + 1];
    const float ad0 = adst[2 * lane], ad1 = adst[2 * lane + 1];
    for (int i = gw; i < N; i += nw) {
        const ushort2 hv = *reinterpret_cast<const ushort2*>(h + (size_t)i * 128 + 2 * lane);
        float h0 = bf2f(hv.x), h1 = bf2f(hv.y);
        float vs = h0 * as0 + h1 * as1;
        float vd = h0 * ad0 + h1 * ad1;
#pragma unroll
        for (int o = 32; o; o >>= 1) {
            vs += __shfl_xor(vs, o);
            vd += __shfl_xor(vd, o);
        }
        if (lane == 0) {
            ssrc[i] = vs;
            sdst[i] = vd;
        }
    }
}

// ---------------- edge score + segment max (encoded atomicMax)
__global__ void edge_max_kernel(const int* __restrict__ ei, const int* __restrict__ flag,
                                const float* __restrict__ ssrc, const float* __restrict__ sdst,
                                float* __restrict__ ebuf, unsigned* __restrict__ menc, int E,
                                int ET, int N) {
    int j = blockIdx.x * 256 + threadIdx.x;
    if (j >= ET) return;
    const int st = *flag;
    int s, d;
    if (j < E) { s = ld_idx(ei, j, st, N); d = ld_idx(ei, E + j, st, N); } else { s = d = j - E; }
    float e = ssrc[s] + sdst[d];
    e = e > 0.f ? e : 0.2f * e;  // leaky_relu 0.2
    ebuf[j] = e;
    atomicMax(&menc[d], encf(e));
}

// ---------------- exp(e - m) + segment sum
__global__ void edge_exp_kernel(const int* __restrict__ ei, const int* __restrict__ flag,
                                const unsigned* __restrict__ menc, float* __restrict__ ebuf,
                                float* __restrict__ den, int E, int ET, int N) {
    int j = blockIdx.x * 256 + threadIdx.x;
    if (j >= ET) return;
    const int st = *flag;
    int d = (j < E) ? ld_idx(ei, E + j, st, N) : j - E;
    float m = decf(menc[d]);
    float ex = __expf(ebuf[j] - m);
    ebuf[j] = ex;
    atomicAdd(&den[d], ex);
}

// ---------------- weighted scatter-add of h[src] into agg[dst] (wave per edge)
__global__ __launch_bounds__(256) void edge_agg_kernel(const int* __restrict__ ei,
                                                       const int* __restrict__ flag,
                                                       const u16* __restrict__ h,
                                                       const float* __restrict__ ebuf,
                                                       const float* __restrict__ den,
                                                       float* __restrict__ agg, int E, int ET,
                                                       int N) {
    const int lane = threadIdx.x & 63;
    const int j = blockIdx.x * 4 + (threadIdx.x >> 6);
    if (j >= ET) return;
    const int st = *flag;
    int s, d;
    if (j < E) { s = ld_idx(ei, j, st, N); d = ld_idx(ei, E + j, st, N); } else { s = d = j - E; }
    float dn = fmaxf(den[d], 1e-30f);
    float alpha = ebuf[j] / dn;
    ushort2 hv = *reinterpret_cast<const ushort2*>(h + (size_t)s * 128 + 2 * lane);
    float* ap = agg + (size_t)d * 128 + 2 * lane;
    atomicAdd(ap, bf2f(hv.x) * alpha);
    atomicAdd(ap + 1, bf2f(hv.y) * alpha);
}

// ---------------- layer-1 epilogue: h1 = relu(agg + b1), stored bf16
__global__ void finalize1_kernel(const float* __restrict__ agg, const float* __restrict__ b,
                                 u16* __restrict__ h1, int total /* N*64 */) {
    int idx = blockIdx.x * 256 + threadIdx.x;
    if (idx >= total) return;
    int c2 = (idx & 63) * 2;
    size_t base = (size_t)idx * 2;
    float v0 = agg[base] + b[c2];
    float v1 = agg[base + 1] + b[c2 + 1];
    v0 = v0 > 0.f ? v0 : 0.f;
    v1 = v1 > 0.f ? v1 : 0.f;
    ushort2 o;
    o.x = f2bf(v0);
    o.y = f2bf(v1);
    *reinterpret_cast<ushort2*>(h1 + base) = o;
}

// ---------------- layer-2 epilogue + skip: o2 = (agg + b2) + h1, stored bf16
__global__ void finalize2_kernel(const float* __restrict__ agg, const float* __restrict__ b,
                                 const u16* __restrict__ h1, u16* __restrict__ o2,
                                 int total /* N*64 */) {
    int idx = blockIdx.x * 256 + threadIdx.x;
    if (idx >= total) return;
    int c2 = (idx & 63) * 2;
    size_t base = (size_t)idx * 2;
    float v0 = agg[base] + b[c2] + bf2f(h1[base]);
    float v1 = agg[base + 1] + b[c2 + 1] + bf2f(h1[base + 1]);
    ushort2 o;
    o.x = f2bf(v0);
    o.y = f2bf(v1);
    *reinterpret_cast<ushort2*>(o2 + base) = o;
}

// ---------------- log_softmax over 64 classes (wave per node, lane = class), f32 out
__global__ __launch_bounds__(256) void logsoftmax_kernel(const float* __restrict__ logits,
                                                         const float* __restrict__ bl,
                                                         float* __restrict__ out, int N) {
    const int lane = threadIdx.x & 63;
    const int i = blockIdx.x * 4 + (threadIdx.x >> 6);
    if (i >= N) return;
    float v = logits[(size_t)i * 64 + lane] + bl[lane];
    float m = v;
#pragma unroll
    for (int o = 32; o; o >>= 1) m = fmaxf(m, __shfl_xor(m, o));
    float ex = __expf(v - m);
    float s = ex;
#pragma unroll
    for (int o = 32; o; o >>= 1) s += __shfl_xor(s, o);
    out[(size_t)i * 64 + lane] = v - m - __logf(s);
}

// ---------------- echo edge_index as f32 (output 1)
__global__ void copy_ei_kernel(const int* __restrict__ ei, const int* __restrict__ flag,
                               float* __restrict__ out, int n, int N) {
    int j = blockIdx.x * 256 + threadIdx.x;
    if (j < n) out[j] = (float)ld_idx(ei, j, *flag, N);
}

extern "C" void kernel_launch(void* const* d_in, const int* in_sizes, int n_in, void* d_out,
                              int out_size, void* d_ws, size_t ws_size, hipStream_t stream) {
    // x is the largest of the first two inputs (guards against x/edge swap)
    int ix = 0, iei = 1;
    if (in_sizes[0] < in_sizes[1]) { ix = 1; iei = 0; }
    const float* x = (const float*)d_in[ix];
    const int* ei = (const int*)d_in[iei];
    const float* W1 = (const float*)d_in[2];
    const float* a1s = (const float*)d_in[3];
    const float* a1d = (const float*)d_in[4];
    const float* b1 = (const float*)d_in[5];
    const float* W2 = (const float*)d_in[6];
    const float* a2s = (const float*)d_in[7];
    const float* a2d = (const float*)d_in[8];
    const float* b2 = (const float*)d_in[9];
    const float* Wl = (const float*)d_in[10];
    const float* bl = (const float*)d_in[11];

    const int N = in_sizes[ix] / 128;
    const int E = (out_size - N * 64) / 2;  // out = [logp N*64 | edge_index 2E], f32
    const int ET = E + N;

    char* ws = (char*)d_ws;
    size_t off = 0;
    auto alloc = [&](size_t bytes) {
        void* p = ws + off;
        off += (bytes + 255) & ~(size_t)255;
        return p;
    };
    u16* h = (u16*)alloc((size_t)N * 128 * 2);    // bf16 gemm out / gather source
    u16* h1 = (u16*)alloc((size_t)N * 128 * 2);   // bf16 layer-1 activation (skip input)
    float* ssrc = (float*)alloc((size_t)N * 4);
    float* sdst = (float*)alloc((size_t)N * 4);
    float* ebuf = (float*)alloc((size_t)ET * 4);
    int* eflag = (int*)alloc(256);
    // contiguous zero-init region: menc | den | agg (one memset per layer)
    char* zbase = ws + off;
    unsigned* menc = (unsigned*)alloc((size_t)N * 4);
    float* den = (float*)alloc((size_t)N * 4);
    float* agg = (float*)alloc((size_t)N * 128 * 4);
    size_t zbytes = (size_t)((ws + off) - zbase);

    float* out_logp = (float*)d_out;
    float* out_ei = out_logp + (size_t)N * 64;

    u16* o2 = h;          // reuse: h (h1@W2) dead after layer-2 aggregation
    float* logits = agg;  // reuse: agg dead after finalize2

    dim3 blk(256);
    const int egrid = (ET + 255) / 256;

    detect_kernel<<<1, 64, 0, stream>>>(ei, eflag);

    // ---- layer 1 ----
    gemm_k128<128, true, false><<<512, blk, 0, stream>>>(x, W1, h, N);
    scores_kernel<<<1024, blk, 0, stream>>>(h, a1s, a1d, ssrc, sdst, N);
    hipMemsetAsync(zbase, 0, zbytes, stream);
    edge_max_kernel<<<egrid, blk, 0, stream>>>(ei, eflag, ssrc, sdst, ebuf, menc, E, ET, N);
    edge_exp_kernel<<<egrid, blk, 0, stream>>>(ei, eflag, menc, ebuf, den, E, ET, N);
    edge_agg_kernel<<<(ET + 3) / 4, blk, 0, stream>>>(ei, eflag, h, ebuf, den, agg, E, ET, N);
    finalize1_kernel<<<(N * 64 + 255) / 256, blk, 0, stream>>>(agg, b1, h1, N * 64);

    // ---- layer 2 ----
    gemm_k128<128, false, false><<<512, blk, 0, stream>>>(h1, W2, h, N);
    scores_kernel<<<1024, blk, 0, stream>>>(h, a2s, a2d, ssrc, sdst, N);
    hipMemsetAsync(zbase, 0, zbytes, stream);
    edge_max_kernel<<<egrid, blk, 0, stream>>>(ei, eflag, ssrc, sdst, ebuf, menc, E, ET, N);
    edge_exp_kernel<<<egrid, blk, 0, stream>>>(ei, eflag, menc, ebuf, den, E, ET, N);
    edge_agg_kernel<<<(ET + 3) / 4, blk, 0, stream>>>(ei, eflag, h, ebuf, den, agg, E, ET, N);
    finalize2_kernel<<<(N * 64 + 255) / 256, blk, 0, stream>>>(agg, b2, h1, o2, N * 64);

    // ---- final linear + log_softmax ----
    gemm_k128<64, false, true><<<512, blk, 0, stream>>>(o2, Wl, (void*)logits, N);
    logsoftmax_kernel<<<(N + 3) / 4, blk, 0, stream>>>(logits, bl, out_logp, N);
    copy_ei_kernel<<<(2 * E + 255) / 256, blk, 0, stream>>>(ei, eflag, out_ei, 2 * E, N);
}

// Round 4
// 605.302 us; speedup vs baseline: 5.4880x; 5.4880x over previous
//
#include <hip/hip_runtime.h>

typedef unsigned short u16;
typedef __bf16 bf16x8 __attribute__((ext_vector_type(8)));
typedef float f32x4 __attribute__((ext_vector_type(4)));
typedef unsigned short u16x8 __attribute__((ext_vector_type(8)));

static __device__ __forceinline__ float bf2f(u16 u) {
    return __uint_as_float(((unsigned)u) << 16);
}
static __device__ __forceinline__ u16 f2bf(float f) {
    unsigned u = __float_as_uint(f);
    unsigned r = (u + 0x7FFFu + ((u >> 16) & 1u)) >> 16;
    return (u16)r;
}

// ---- edge_index word-stride detection: int32-packed (1) vs int64-as-2-words (2)
__global__ void detect_kernel(const int* __restrict__ ei, int* __restrict__ flag) {
    if (blockIdx.x == 0 && threadIdx.x == 0) {
        int zc = 0;
        for (int t = 0; t < 64; ++t) zc += (ei[2 * t + 1] == 0) ? 1 : 0;
        *flag = (zc >= 60) ? 2 : 1;
    }
}
static __device__ __forceinline__ int ld_idx(const int* ei, int pos, int st, int N) {
    int v = ei[(size_t)pos * (size_t)st];
    return v < 0 ? 0 : (v >= N ? N - 1 : v);
}

// ================= CSR build (counting sort on dst; self-loops appended) ======
__global__ void hist_kernel(const int* __restrict__ ei, const int* __restrict__ flag,
                            int* __restrict__ deg, int E, int ET, int N) {
    int j = blockIdx.x * 256 + threadIdx.x;
    if (j >= ET) return;
    int st = *flag;
    int d = (j < E) ? ld_idx(ei, E + j, st, N) : j - E;
    atomicAdd(&deg[d], 1);
}

#define SCHUNK 4096
__global__ void scan_reduce_kernel(const int* __restrict__ deg, int* __restrict__ bsum, int N) {
    __shared__ int sdata[256];
    int t = threadIdx.x;
    int base = blockIdx.x * SCHUNK + t * 16;
    int s = 0;
#pragma unroll
    for (int j = 0; j < 16; ++j) { int i = base + j; s += (i < N) ? deg[i] : 0; }
    sdata[t] = s;
    __syncthreads();
    for (int o = 128; o > 0; o >>= 1) {
        if (t < o) sdata[t] += sdata[t + o];
        __syncthreads();
    }
    if (t == 0) bsum[blockIdx.x] = sdata[0];
}
__global__ void scan_mid_kernel(int* __restrict__ bsum, int nb) {
    if (threadIdx.x == 0 && blockIdx.x == 0) {
        int run = 0;
        for (int b = 0; b < nb; ++b) { int v = bsum[b]; bsum[b] = run; run += v; }
    }
}
__global__ void scan_final_kernel(const int* __restrict__ deg, const int* __restrict__ bsum,
                                  int* __restrict__ rowptr, int* __restrict__ cursor, int N,
                                  int ET) {
    __shared__ int sdata[256];
    int t = threadIdx.x;
    int base = blockIdx.x * SCHUNK + t * 16;
    int v[16];
    int s = 0;
#pragma unroll
    for (int j = 0; j < 16; ++j) {
        int i = base + j;
        v[j] = (i < N) ? deg[i] : 0;
        s += v[j];
    }
    sdata[t] = s;
    __syncthreads();
    for (int o = 1; o < 256; o <<= 1) {
        int add = (t >= o) ? sdata[t - o] : 0;
        __syncthreads();
        sdata[t] += add;
        __syncthreads();
    }
    int excl = (t == 0) ? 0 : sdata[t - 1];
    int off = bsum[blockIdx.x] + excl;
#pragma unroll
    for (int j = 0; j < 16; ++j) {
        int i = base + j;
        if (i < N) {
            rowptr[i] = off;
            cursor[i] = off;
            off += v[j];
        }
    }
    if (blockIdx.x == 0 && t == 0) rowptr[N] = ET;
}
__global__ void scatter_kernel(const int* __restrict__ ei, const int* __restrict__ flag,
                               int* __restrict__ cursor, int* __restrict__ col, int E, int ET,
                               int N) {
    int j = blockIdx.x * 256 + threadIdx.x;
    if (j >= ET) return;
    int st = *flag;
    int s, d;
    if (j < E) { s = ld_idx(ei, j, st, N); d = ld_idx(ei, E + j, st, N); } else { s = d = j - E; }
    int pos = atomicAdd(&cursor[d], 1);
    col[pos] = s;
}

// ---------------- GEMM: C[M,NC] = A[M,128] @ W[128,NC]
// MFMA 16x16x32 bf16. A: A[m=lane&15][k=quad*8+j]; B: B[k=quad*8+j][n=lane&15];
// D: col=lane&15, row=quad*4+reg. W (f32) converted to register-resident bf16 frags.
template <int NC, bool AF32, bool OUTF32>
__global__ __launch_bounds__(256) void gemm_k128(const void* __restrict__ Ap,
                                                 const float* __restrict__ W,
                                                 void* __restrict__ Cout, int M) {
    const int lane = threadIdx.x & 63;
    const int quad = lane >> 4;
    const int r = lane & 15;
    const int gw = (blockIdx.x * 256 + threadIdx.x) >> 6;
    const int nw = (gridDim.x * 256) >> 6;

    bf16x8 bf[NC / 16][4];
#pragma unroll
    for (int nt = 0; nt < NC / 16; ++nt)
#pragma unroll
        for (int kk = 0; kk < 4; ++kk) {
            union { bf16x8 v; u16 s[8]; } u;
#pragma unroll
            for (int j = 0; j < 8; ++j)
                u.s[j] = f2bf(W[(size_t)(kk * 32 + quad * 8 + j) * NC + nt * 16 + r]);
            bf[nt][kk] = u.v;
        }

    const int ntiles = (M + 15) >> 4;
    for (int t = gw; t < ntiles; t += nw) {
        const int row0 = t << 4;
        bf16x8 af[4];
        if (AF32) {
            const float* arow = (const float*)Ap + (size_t)(row0 + r) * 128;
#pragma unroll
            for (int kk = 0; kk < 4; ++kk) {
                f32x4 f0 = *reinterpret_cast<const f32x4*>(arow + kk * 32 + quad * 8);
                f32x4 f1 = *reinterpret_cast<const f32x4*>(arow + kk * 32 + quad * 8 + 4);
                union { bf16x8 v; u16 s[8]; } u;
#pragma unroll
                for (int j = 0; j < 4; ++j) { u.s[j] = f2bf(f0[j]); u.s[4 + j] = f2bf(f1[j]); }
                af[kk] = u.v;
            }
        } else {
            const u16* arow = (const u16*)Ap + (size_t)(row0 + r) * 128;
#pragma unroll
            for (int kk = 0; kk < 4; ++kk)
                af[kk] = *reinterpret_cast<const bf16x8*>(arow + kk * 32 + quad * 8);
        }
        f32x4 acc[NC / 16];
#pragma unroll
        for (int nt = 0; nt < NC / 16; ++nt) acc[nt] = (f32x4){0.f, 0.f, 0.f, 0.f};
#pragma unroll
        for (int kk = 0; kk < 4; ++kk)
#pragma unroll
            for (int nt = 0; nt < NC / 16; ++nt)
                acc[nt] = __builtin_amdgcn_mfma_f32_16x16x32_bf16(af[kk], bf[nt][kk],
                                                                  acc[nt], 0, 0, 0);
#pragma unroll
        for (int nt = 0; nt < NC / 16; ++nt)
#pragma unroll
            for (int reg = 0; reg < 4; ++reg) {
                int row = row0 + quad * 4 + reg;
                int col = nt * 16 + r;
                if (OUTF32)
                    ((float*)Cout)[(size_t)row * NC + col] = acc[nt][reg];
                else
                    ((u16*)Cout)[(size_t)row * NC + col] = f2bf(acc[nt][reg]);
            }
    }
}

// ---------------- per-node attention scores s_src = h.a_src, s_dst = h.a_dst
__global__ __launch_bounds__(256) void scores_kernel(const u16* __restrict__ h,
                                                     const float* __restrict__ asrc,
                                                     const float* __restrict__ adst,
                                                     float* __restrict__ ssrc,
                                                     float* __restrict__ sdst, int N) {
    const int lane = threadIdx.x & 63;
    const int gw = (blockIdx.x * 256 + threadIdx.x) >> 6;
    const int nw = (gridDim.x * 256) >> 6;
    const float as0 = asrc[2 * lane], as1 = asrc[2 * lane + 1];
    const float ad0 = adst[2 * lane], ad1 = adst[2 * lane + 1];
    for (int i = gw; i < N; i += nw) {
        const ushort2 hv = *reinterpret_cast<const ushort2*>(h + (size_t)i * 128 + 2 * lane);
        float h0 = bf2f(hv.x), h1 = bf2f(hv.y);
        float vs = h0 * as0 + h1 * as1;
        float vd = h0 * ad0 + h1 * ad1;
#pragma unroll
        for (int o = 32; o; o >>= 1) {
            vs += __shfl_xor(vs, o);
            vd += __shfl_xor(vd, o);
        }
        if (lane == 0) {
            ssrc[i] = vs;
            sdst[i] = vd;
        }
    }
}

// ---------------- per-node softmax stats over CSR (16-lane group per node)
__global__ __launch_bounds__(256) void attn_csr_kernel(const int* __restrict__ rowptr,
                                                       const int* __restrict__ col,
                                                       const float* __restrict__ ssrc,
                                                       const float* __restrict__ sdst,
                                                       float* __restrict__ mx,
                                                       float* __restrict__ rden, int N) {
    const int lane = threadIdx.x & 63;
    const int gwave = (blockIdx.x * 256 + threadIdx.x) >> 6;
    const int grp = lane >> 4;
    const int ln = lane & 15;
    const int i = gwave * 4 + grp;
    if (i >= N) return;
    const int start = rowptr[i], end = rowptr[i + 1];
    const float sd = sdst[i];
    float m = -3.4e38f;
    for (int e = start + ln; e < end; e += 16) {
        float sc = ssrc[col[e]] + sd;
        sc = sc > 0.f ? sc : 0.2f * sc;
        m = fmaxf(m, sc);
    }
#pragma unroll
    for (int o = 1; o < 16; o <<= 1) m = fmaxf(m, __shfl_xor(m, o));
    float sm = 0.f;
    for (int e = start + ln; e < end; e += 16) {
        float sc = ssrc[col[e]] + sd;
        sc = sc > 0.f ? sc : 0.2f * sc;
        sm += __expf(sc - m);
    }
#pragma unroll
    for (int o = 1; o < 16; o <<= 1) sm += __shfl_xor(sm, o);
    if (ln == 0) {
        mx[i] = m;
        rden[i] = 1.f / sm;
    }
}

// ---------------- CSR aggregation: 16-lane group per dst node, lane = 8 channels.
// MODE 1: out = relu(acc + b)  (layer 1).  MODE 2: out = acc + b + skip (layer 2).
template <int MODE>
__global__ __launch_bounds__(256) void agg_csr_kernel(
    const int* __restrict__ rowptr, const int* __restrict__ col,
    const float* __restrict__ ssrc, const float* __restrict__ sdst,
    const float* __restrict__ mx, const float* __restrict__ rden, const u16* __restrict__ h,
    const float* __restrict__ b, const u16* __restrict__ skip, u16* __restrict__ out, int N) {
    const int lane = threadIdx.x & 63;
    const int gwave = (blockIdx.x * 256 + threadIdx.x) >> 6;
    const int grp = lane >> 4;
    const int ln = lane & 15;
    const int i = gwave * 4 + grp;
    if (i >= N) return;
    const int start = rowptr[i], end = rowptr[i + 1];
    const float sd = sdst[i], m = mx[i], rd = rden[i];
    const size_t coff = (size_t)ln * 8;
    float acc[8] = {0.f, 0.f, 0.f, 0.f, 0.f, 0.f, 0.f, 0.f};
    int e = start;
    for (; e + 2 <= end; e += 2) {
        int c0 = col[e], c1 = col[e + 1];
        float s0 = ssrc[c0] + sd;
        float s1 = ssrc[c1] + sd;
        s0 = s0 > 0.f ? s0 : 0.2f * s0;
        s1 = s1 > 0.f ? s1 : 0.2f * s1;
        float w0 = __expf(s0 - m) * rd;
        float w1 = __expf(s1 - m) * rd;
        u16x8 r0 = *reinterpret_cast<const u16x8*>(h + (size_t)c0 * 128 + coff);
        u16x8 r1 = *reinterpret_cast<const u16x8*>(h + (size_t)c1 * 128 + coff);
#pragma unroll
        for (int j = 0; j < 8; ++j) acc[j] += w0 * bf2f(r0[j]) + w1 * bf2f(r1[j]);
    }
    if (e < end) {
        int c0 = col[e];
        float s0 = ssrc[c0] + sd;
        s0 = s0 > 0.f ? s0 : 0.2f * s0;
        float w0 = __expf(s0 - m) * rd;
        u16x8 r0 = *reinterpret_cast<const u16x8*>(h + (size_t)c0 * 128 + coff);
#pragma unroll
        for (int j = 0; j < 8; ++j) acc[j] += w0 * bf2f(r0[j]);
    }
    u16x8 o;
    if (MODE == 1) {
#pragma unroll
        for (int j = 0; j < 8; ++j) {
            float v = acc[j] + b[coff + j];
            v = v > 0.f ? v : 0.f;
            o[j] = f2bf(v);
        }
    } else {
        const u16x8 sk = *reinterpret_cast<const u16x8*>(skip + (size_t)i * 128 + coff);
#pragma unroll
        for (int j = 0; j < 8; ++j) {
            float v = acc[j] + b[coff + j] + bf2f(sk[j]);
            o[j] = f2bf(v);
        }
    }
    *reinterpret_cast<u16x8*>(out + (size_t)i * 128 + coff) = o;
}

// ---------------- log_softmax over 64 classes (wave per node, lane = class), f32 out
__global__ __launch_bounds__(256) void logsoftmax_kernel(const float* __restrict__ logits,
                                                         const float* __restrict__ bl,
                                                         float* __restrict__ out, int N) {
    const int lane = threadIdx.x & 63;
    const int i = blockIdx.x * 4 + (threadIdx.x >> 6);
    if (i >= N) return;
    float v = logits[(size_t)i * 64 + lane] + bl[lane];
    float m = v;
#pragma unroll
    for (int o = 32; o; o >>= 1) m = fmaxf(m, __shfl_xor(m, o));
    float ex = __expf(v - m);
    float s = ex;
#pragma unroll
    for (int o = 32; o; o >>= 1) s += __shfl_xor(s, o);
    out[(size_t)i * 64 + lane] = v - m - __logf(s);
}

// ---------------- echo edge_index as f32 (output 1)
__global__ void copy_ei_kernel(const int* __restrict__ ei, const int* __restrict__ flag,
                               float* __restrict__ out, int n, int N) {
    int j = blockIdx.x * 256 + threadIdx.x;
    if (j < n) out[j] = (float)ld_idx(ei, j, *flag, N);
}

extern "C" void kernel_launch(void* const* d_in, const int* in_sizes, int n_in, void* d_out,
                              int out_size, void* d_ws, size_t ws_size, hipStream_t stream) {
    int ix = 0, iei = 1;
    if (in_sizes[0] < in_sizes[1]) { ix = 1; iei = 0; }
    const float* x = (const float*)d_in[ix];
    const int* ei = (const int*)d_in[iei];
    const float* W1 = (const float*)d_in[2];
    const float* a1s = (const float*)d_in[3];
    const float* a1d = (const float*)d_in[4];
    const float* b1 = (const float*)d_in[5];
    const float* W2 = (const float*)d_in[6];
    const float* a2s = (const float*)d_in[7];
    const float* a2d = (const float*)d_in[8];
    const float* b2 = (const float*)d_in[9];
    const float* Wl = (const float*)d_in[10];
    const float* bl = (const float*)d_in[11];

    const int N = in_sizes[ix] / 128;
    const int E = (out_size - N * 64) / 2;  // out = [logp N*64 | edge_index 2E], f32
    const int ET = E + N;

    char* ws = (char*)d_ws;
    size_t off = 0;
    auto alloc = [&](size_t bytes) {
        void* p = ws + off;
        off += (bytes + 255) & ~(size_t)255;
        return p;
    };
    u16* h = (u16*)alloc((size_t)N * 128 * 2);   // bf16 gemm out / gather source
    u16* h1 = (u16*)alloc((size_t)N * 128 * 2);  // bf16 layer-1 activation (skip input)
    u16* o2 = (u16*)alloc((size_t)N * 128 * 2);  // bf16 layer-2 out (final gemm input)
    float* ssrc = (float*)alloc((size_t)N * 4);
    float* sdst = (float*)alloc((size_t)N * 4);
    float* mx = (float*)alloc((size_t)N * 4);
    float* rden = (float*)alloc((size_t)N * 4);
    int* eflag = (int*)alloc(256);
    int* deg = (int*)alloc((size_t)N * 4);     // histogram
    int* cursor = (int*)alloc((size_t)N * 4);  // scatter cursors
    int* rowptr = (int*)alloc((size_t)(N + 1) * 4);
    int* bsum = (int*)alloc(4096);
    int* colv = (int*)alloc((size_t)ET * 4);
    float* logits = (float*)h;  // reuse: h dead after layer-2 agg consumes it

    float* out_logp = (float*)d_out;
    float* out_ei = out_logp + (size_t)N * 64;

    dim3 blk(256);
    const int egrid = (ET + 255) / 256;
    const int ngrid4 = (N + 15) / 16;  // 4 nodes per wave, 4 waves per block
    const int nb = (N + SCHUNK - 1) / SCHUNK;

    // ---- CSR build (once; reused by both layers) ----
    detect_kernel<<<1, 64, 0, stream>>>(ei, eflag);
    hipMemsetAsync(deg, 0, (size_t)N * 4, stream);
    hist_kernel<<<egrid, blk, 0, stream>>>(ei, eflag, deg, E, ET, N);
    scan_reduce_kernel<<<nb, blk, 0, stream>>>(deg, bsum, N);
    scan_mid_kernel<<<1, 64, 0, stream>>>(bsum, nb);
    scan_final_kernel<<<nb, blk, 0, stream>>>(deg, bsum, rowptr, cursor, N, ET);
    scatter_kernel<<<egrid, blk, 0, stream>>>(ei, eflag, cursor, colv, E, ET, N);

    // ---- layer 1 ----
    gemm_k128<128, true, false><<<512, blk, 0, stream>>>(x, W1, h, N);
    scores_kernel<<<1024, blk, 0, stream>>>(h, a1s, a1d, ssrc, sdst, N);
    attn_csr_kernel<<<ngrid4, blk, 0, stream>>>(rowptr, colv, ssrc, sdst, mx, rden, N);
    agg_csr_kernel<1><<<ngrid4, blk, 0, stream>>>(rowptr, colv, ssrc, sdst, mx, rden, h, b1,
                                                  (const u16*)nullptr, h1, N);

    // ---- layer 2 ----
    gemm_k128<128, false, false><<<512, blk, 0, stream>>>(h1, W2, h, N);
    scores_kernel<<<1024, blk, 0, stream>>>(h, a2s, a2d, ssrc, sdst, N);
    attn_csr_kernel<<<ngrid4, blk, 0, stream>>>(rowptr, colv, ssrc, sdst, mx, rden, N);
    agg_csr_kernel<2><<<ngrid4, blk, 0, stream>>>(rowptr, colv, ssrc, sdst, mx, rden, h, b2,
                                                  h1, o2, N);

    // ---- final linear + log_softmax ----
    gemm_k128<64, false, true><<<512, blk, 0, stream>>>(o2, Wl, (void*)logits, N);
    logsoftmax_kernel<<<(N + 3) / 4, blk, 0, stream>>>(logits, bl, out_logp, N);
    copy_ei_kernel<<<(2 * E + 255) / 256, blk, 0, stream>>>(ei, eflag, out_ei, 2 * E, N);
}

// Round 5
// 483.224 us; speedup vs baseline: 6.8744x; 1.2526x over previous
//
#include <hip/hip_runtime.h>

typedef unsigned short u16;
typedef __bf16 bf16x8 __attribute__((ext_vector_type(8)));
typedef float f32x4 __attribute__((ext_vector_type(4)));
typedef unsigned short u16x8 __attribute__((ext_vector_type(8)));

static __device__ __forceinline__ float bf2f(u16 u) {
    return __uint_as_float(((unsigned)u) << 16);
}
static __device__ __forceinline__ u16 f2bf(float f) {
    unsigned u = __float_as_uint(f);
    unsigned r = (u + 0x7FFFu + ((u >> 16) & 1u)) >> 16;
    return (u16)r;
}

// ---- edge_index word-stride detection: int32-packed (1) vs int64-as-2-words (2)
__global__ void detect_kernel(const int* __restrict__ ei, int* __restrict__ flag) {
    if (blockIdx.x == 0 && threadIdx.x == 0) {
        int zc = 0;
        for (int t = 0; t < 64; ++t) zc += (ei[2 * t + 1] == 0) ? 1 : 0;
        *flag = (zc >= 60) ? 2 : 1;
    }
}
static __device__ __forceinline__ int ld_idx(const int* ei, int pos, int st, int N) {
    int v = ei[(size_t)pos * (size_t)st];
    return v < 0 ? 0 : (v >= N ? N - 1 : v);
}

// ================= CSR scan (rowptr from deg) ================================
#define SCHUNK 4096
__global__ void scan_reduce_kernel(const int* __restrict__ deg, int* __restrict__ bsum, int N) {
    __shared__ int sdata[256];
    int t = threadIdx.x;
    int base = blockIdx.x * SCHUNK + t * 16;
    int s = 0;
#pragma unroll
    for (int j = 0; j < 16; ++j) { int i = base + j; s += (i < N) ? deg[i] : 0; }
    sdata[t] = s;
    __syncthreads();
    for (int o = 128; o > 0; o >>= 1) {
        if (t < o) sdata[t] += sdata[t + o];
        __syncthreads();
    }
    if (t == 0) bsum[blockIdx.x] = sdata[0];
}
__global__ void scan_mid_kernel(int* __restrict__ bsum, int nb) {
    if (threadIdx.x == 0 && blockIdx.x == 0) {
        int run = 0;
        for (int b = 0; b < nb; ++b) { int v = bsum[b]; bsum[b] = run; run += v; }
    }
}
__global__ void scan_final_kernel(const int* __restrict__ deg, const int* __restrict__ bsum,
                                  int* __restrict__ rowptr, int* __restrict__ cursor, int N,
                                  int ET) {
    __shared__ int sdata[256];
    int t = threadIdx.x;
    int base = blockIdx.x * SCHUNK + t * 16;
    int v[16];
    int s = 0;
#pragma unroll
    for (int j = 0; j < 16; ++j) {
        int i = base + j;
        v[j] = (i < N) ? deg[i] : 0;
        s += v[j];
    }
    sdata[t] = s;
    __syncthreads();
    for (int o = 1; o < 256; o <<= 1) {
        int add = (t >= o) ? sdata[t - o] : 0;
        __syncthreads();
        sdata[t] += add;
        __syncthreads();
    }
    int excl = (t == 0) ? 0 : sdata[t - 1];
    int off = bsum[blockIdx.x] + excl;
#pragma unroll
    for (int j = 0; j < 16; ++j) {
        int i = base + j;
        if (i < N) {
            rowptr[i] = off;
            cursor[i] = off;
            off += v[j];
        }
    }
    if (blockIdx.x == 0 && t == 0) rowptr[N] = ET;
}

// ---- phase-partitioned scatter: 8 dst-range phases; WG's edge chunk stays in L1,
// writes per phase land in a ~850KB slice of col -> dense line accumulation.
__global__ __launch_bounds__(256) void scatter_phased(const int* __restrict__ ei,
                                                      const int* __restrict__ flag,
                                                      int* __restrict__ cursor,
                                                      int* __restrict__ col, int E, int ET,
                                                      int N, int nwg) {
    const int st = *flag;
    const int chunk = (ET + nwg - 1) / nwg;
    const int c0 = blockIdx.x * chunk;
    const int c1 = c0 + chunk < ET ? c0 + chunk : ET;
    const int Np = (N + 7) >> 3;
    for (int p = 0; p < 8; ++p) {
        const int lo = p * Np;
        const int hi = lo + Np < N ? lo + Np : N;
        for (int j = c0 + (int)threadIdx.x; j < c1; j += 256) {
            int d = (j < E) ? ld_idx(ei, E + j, st, N) : (j - E);
            if (d >= lo && d < hi) {
                int s = (j < E) ? ld_idx(ei, j, st, N) : d;
                int pos = atomicAdd(&cursor[d], 1);
                col[pos] = s;
            }
        }
    }
}

// ---------------- fused GEMM: C[M,NC] = A[M,128] @ W[128,NC]
// MFMA 16x16x32 bf16. A: A[m=lane&15][k=quad*8+j]; B: B[k=quad*8+j][n=lane&15];
// D: col=lane&15, row=quad*4+reg. W (f32) -> register-resident bf16 frags.
// EPI 1: store C bf16 + per-row scores (s_src,s_dst) via quad-lane reduction.
// EPI 2: no C store; fused log_softmax over NC=64 cols -> outp f32.
// HIST: blocks >= G1 instead histogram dst into deg (independent work, overlapped).
template <int NC, bool AF32, int EPI, bool HIST>
__global__ __launch_bounds__(256) void gemm_fused(
    const void* __restrict__ Ap, const float* __restrict__ W, u16* __restrict__ Cout, int M,
    const float* __restrict__ av_s, const float* __restrict__ av_d, float* __restrict__ ssrc,
    float* __restrict__ sdst, const float* __restrict__ bl, float* __restrict__ outp,
    const int* __restrict__ ei, const int* __restrict__ flag, int* __restrict__ deg, int E,
    int ET, int N, int G1) {
    if (HIST && (int)blockIdx.x >= G1) {
        int tid = ((int)blockIdx.x - G1) * 256 + threadIdx.x;
        int stride = ((int)gridDim.x - G1) * 256;
        int st = *flag;
        for (int j = tid; j < ET; j += stride) {
            int d = (j < E) ? ld_idx(ei, E + j, st, N) : j - E;
            atomicAdd(&deg[d], 1);
        }
        return;
    }
    const int lane = threadIdx.x & 63;
    const int quad = lane >> 4;
    const int r = lane & 15;
    const int gw = (blockIdx.x * 256 + threadIdx.x) >> 6;
    const int nw = G1 * 4;

    bf16x8 bf[NC / 16][4];
#pragma unroll
    for (int nt = 0; nt < NC / 16; ++nt)
#pragma unroll
        for (int kk = 0; kk < 4; ++kk) {
            union { bf16x8 v; u16 s[8]; } u;
#pragma unroll
            for (int j = 0; j < 8; ++j)
                u.s[j] = f2bf(W[(size_t)(kk * 32 + quad * 8 + j) * NC + nt * 16 + r]);
            bf[nt][kk] = u.v;
        }
    float avs[NC / 16], avd[NC / 16], blv[NC / 16];
    if (EPI == 1) {
#pragma unroll
        for (int nt = 0; nt < NC / 16; ++nt) {
            avs[nt] = av_s[nt * 16 + r];
            avd[nt] = av_d[nt * 16 + r];
        }
    }
    if (EPI == 2) {
#pragma unroll
        for (int nt = 0; nt < NC / 16; ++nt) blv[nt] = bl[nt * 16 + r];
    }

    const int ntiles = (M + 15) >> 4;
    for (int t = gw; t < ntiles; t += nw) {
        const int row0 = t << 4;
        bf16x8 af[4];
        if (AF32) {
            const float* arow = (const float*)Ap + (size_t)(row0 + r) * 128;
#pragma unroll
            for (int kk = 0; kk < 4; ++kk) {
                f32x4 f0 = *reinterpret_cast<const f32x4*>(arow + kk * 32 + quad * 8);
                f32x4 f1 = *reinterpret_cast<const f32x4*>(arow + kk * 32 + quad * 8 + 4);
                union { bf16x8 v; u16 s[8]; } u;
#pragma unroll
                for (int j = 0; j < 4; ++j) { u.s[j] = f2bf(f0[j]); u.s[4 + j] = f2bf(f1[j]); }
                af[kk] = u.v;
            }
        } else {
            const u16* arow = (const u16*)Ap + (size_t)(row0 + r) * 128;
#pragma unroll
            for (int kk = 0; kk < 4; ++kk)
                af[kk] = *reinterpret_cast<const bf16x8*>(arow + kk * 32 + quad * 8);
        }
        f32x4 acc[NC / 16];
#pragma unroll
        for (int nt = 0; nt < NC / 16; ++nt) acc[nt] = (f32x4){0.f, 0.f, 0.f, 0.f};
#pragma unroll
        for (int kk = 0; kk < 4; ++kk)
#pragma unroll
            for (int nt = 0; nt < NC / 16; ++nt)
                acc[nt] = __builtin_amdgcn_mfma_f32_16x16x32_bf16(af[kk], bf[nt][kk],
                                                                  acc[nt], 0, 0, 0);
        if (EPI != 2) {
#pragma unroll
            for (int nt = 0; nt < NC / 16; ++nt)
#pragma unroll
                for (int reg = 0; reg < 4; ++reg)
                    Cout[(size_t)(row0 + quad * 4 + reg) * NC + nt * 16 + r] =
                        f2bf(acc[nt][reg]);
        }
        if (EPI == 1) {
            float ps[4] = {0.f, 0.f, 0.f, 0.f}, pd[4] = {0.f, 0.f, 0.f, 0.f};
#pragma unroll
            for (int nt = 0; nt < NC / 16; ++nt)
#pragma unroll
                for (int reg = 0; reg < 4; ++reg) {
                    ps[reg] += acc[nt][reg] * avs[nt];
                    pd[reg] += acc[nt][reg] * avd[nt];
                }
#pragma unroll
            for (int o = 1; o < 16; o <<= 1)
#pragma unroll
                for (int reg = 0; reg < 4; ++reg) {
                    ps[reg] += __shfl_xor(ps[reg], o);
                    pd[reg] += __shfl_xor(pd[reg], o);
                }
            if (r == 0) {
#pragma unroll
                for (int reg = 0; reg < 4; ++reg) {
                    ssrc[row0 + quad * 4 + reg] = ps[reg];
                    sdst[row0 + quad * 4 + reg] = pd[reg];
                }
            }
        }
        if (EPI == 2) {
#pragma unroll
            for (int reg = 0; reg < 4; ++reg) {
                float v[NC / 16];
                float m = -3.4e38f;
#pragma unroll
                for (int nt = 0; nt < NC / 16; ++nt) {
                    v[nt] = acc[nt][reg] + blv[nt];
                    m = fmaxf(m, v[nt]);
                }
#pragma unroll
                for (int o = 1; o < 16; o <<= 1) m = fmaxf(m, __shfl_xor(m, o));
                float s = 0.f;
#pragma unroll
                for (int nt = 0; nt < NC / 16; ++nt) s += __expf(v[nt] - m);
#pragma unroll
                for (int o = 1; o < 16; o <<= 1) s += __shfl_xor(s, o);
                float L = __logf(s);
                const size_t rb = (size_t)(row0 + quad * 4 + reg) * NC;
#pragma unroll
                for (int nt = 0; nt < NC / 16; ++nt)
                    outp[rb + nt * 16 + r] = v[nt] - m - L;
            }
        }
    }
}

// ---------------- fused denom+agg over CSR: 16-lane group per dst node.
// pass A: denom = sum(exp(leaky(score))); pass B: weighted gather-accumulate.
// MODE 1: out = relu(acc + b).  MODE 2: out = acc + b + skip.
template <int MODE>
__global__ __launch_bounds__(256) void agg_fused(
    const int* __restrict__ rowptr, const int* __restrict__ col,
    const float* __restrict__ ssrc, const float* __restrict__ sdst,
    const u16* __restrict__ h, const float* __restrict__ b, const u16* __restrict__ skip,
    u16* __restrict__ out, int N) {
    const int lane = threadIdx.x & 63;
    const int gwave = (blockIdx.x * 256 + threadIdx.x) >> 6;
    const int grp = lane >> 4;
    const int ln = lane & 15;
    const int i = gwave * 4 + grp;
    if (i >= N) return;
    const int start = rowptr[i], end = rowptr[i + 1];
    const float sd = sdst[i];
    float sm = 0.f;
    for (int e = start + ln; e < end; e += 16) {
        float sc = ssrc[col[e]] + sd;
        sc = sc > 0.f ? sc : 0.2f * sc;
        sm += __expf(fminf(sc, 60.f));
    }
#pragma unroll
    for (int o = 1; o < 16; o <<= 1) sm += __shfl_xor(sm, o);
    const float rd = 1.f / sm;

    const size_t coff = (size_t)ln * 8;
    float acc[8] = {0.f, 0.f, 0.f, 0.f, 0.f, 0.f, 0.f, 0.f};
    int e = start;
    for (; e + 2 <= end; e += 2) {
        int c0 = col[e], c1 = col[e + 1];
        float s0 = ssrc[c0] + sd;
        float s1 = ssrc[c1] + sd;
        s0 = s0 > 0.f ? s0 : 0.2f * s0;
        s1 = s1 > 0.f ? s1 : 0.2f * s1;
        float w0 = __expf(fminf(s0, 60.f)) * rd;
        float w1 = __expf(fminf(s1, 60.f)) * rd;
        u16x8 r0 = *reinterpret_cast<const u16x8*>(h + (size_t)c0 * 128 + coff);
        u16x8 r1 = *reinterpret_cast<const u16x8*>(h + (size_t)c1 * 128 + coff);
#pragma unroll
        for (int j = 0; j < 8; ++j) acc[j] += w0 * bf2f(r0[j]) + w1 * bf2f(r1[j]);
    }
    if (e < end) {
        int c0 = col[e];
        float s0 = ssrc[c0] + sd;
        s0 = s0 > 0.f ? s0 : 0.2f * s0;
        float w0 = __expf(fminf(s0, 60.f)) * rd;
        u16x8 r0 = *reinterpret_cast<const u16x8*>(h + (size_t)c0 * 128 + coff);
#pragma unroll
        for (int j = 0; j < 8; ++j) acc[j] += w0 * bf2f(r0[j]);
    }
    u16x8 o;
    if (MODE == 1) {
#pragma unroll
        for (int j = 0; j < 8; ++j) {
            float v = acc[j] + b[coff + j];
            v = v > 0.f ? v : 0.f;
            o[j] = f2bf(v);
        }
    } else {
        const u16x8 sk = *reinterpret_cast<const u16x8*>(skip + (size_t)i * 128 + coff);
#pragma unroll
        for (int j = 0; j < 8; ++j) {
            float v = acc[j] + b[coff + j] + bf2f(sk[j]);
            o[j] = f2bf(v);
        }
    }
    *reinterpret_cast<u16x8*>(out + (size_t)i * 128 + coff) = o;
}

// ---------------- echo edge_index as f32 (output 1)
__global__ void copy_ei_kernel(const int* __restrict__ ei, const int* __restrict__ flag,
                               float* __restrict__ out, int n, int N) {
    int j = blockIdx.x * 256 + threadIdx.x;
    if (j < n) out[j] = (float)ld_idx(ei, j, *flag, N);
}

extern "C" void kernel_launch(void* const* d_in, const int* in_sizes, int n_in, void* d_out,
                              int out_size, void* d_ws, size_t ws_size, hipStream_t stream) {
    int ix = 0, iei = 1;
    if (in_sizes[0] < in_sizes[1]) { ix = 1; iei = 0; }
    const float* x = (const float*)d_in[ix];
    const int* ei = (const int*)d_in[iei];
    const float* W1 = (const float*)d_in[2];
    const float* a1s = (const float*)d_in[3];
    const float* a1d = (const float*)d_in[4];
    const float* b1 = (const float*)d_in[5];
    const float* W2 = (const float*)d_in[6];
    const float* a2s = (const float*)d_in[7];
    const float* a2d = (const float*)d_in[8];
    const float* b2 = (const float*)d_in[9];
    const float* Wl = (const float*)d_in[10];
    const float* bl = (const float*)d_in[11];

    const int N = in_sizes[ix] / 128;
    const int E = (out_size - N * 64) / 2;  // out = [logp N*64 | edge_index 2E], f32
    const int ET = E + N;

    char* ws = (char*)d_ws;
    size_t off = 0;
    auto alloc = [&](size_t bytes) {
        void* p = ws + off;
        off += (bytes + 255) & ~(size_t)255;
        return p;
    };
    u16* h = (u16*)alloc((size_t)N * 128 * 2);   // bf16 gemm out / gather source
    u16* h1 = (u16*)alloc((size_t)N * 128 * 2);  // bf16 layer-1 activation (skip input)
    u16* o2 = (u16*)alloc((size_t)N * 128 * 2);  // bf16 layer-2 out (final gemm input)
    float* ssrc = (float*)alloc((size_t)N * 4);
    float* sdst = (float*)alloc((size_t)N * 4);
    int* eflag = (int*)alloc(256);
    int* deg = (int*)alloc((size_t)N * 4);
    int* cursor = (int*)alloc((size_t)N * 4);
    int* rowptr = (int*)alloc((size_t)(N + 1) * 4);
    int* bsum = (int*)alloc(4096);
    int* colv = (int*)alloc((size_t)ET * 4);

    float* out_logp = (float*)d_out;
    float* out_ei = out_logp + (size_t)N * 64;

    dim3 blk(256);
    const int ngrid4 = (N + 15) / 16;  // 16-lane group per node, 16 nodes/block
    const int nb = (N + SCHUNK - 1) / SCHUNK;
    const int G1 = 512;  // gemm blocks in fused gemm+hist

    detect_kernel<<<1, 64, 0, stream>>>(ei, eflag);
    hipMemsetAsync(deg, 0, (size_t)N * 4, stream);

    // ---- layer-1 GEMM (+scores epilogue) fused with dst histogram ----
    gemm_fused<128, true, 1, true><<<G1 + 512, blk, 0, stream>>>(
        x, W1, h, N, a1s, a1d, ssrc, sdst, nullptr, nullptr, ei, eflag, deg, E, ET, N, G1);

    // ---- CSR scan + phase-partitioned scatter ----
    scan_reduce_kernel<<<nb, blk, 0, stream>>>(deg, bsum, N);
    scan_mid_kernel<<<1, 64, 0, stream>>>(bsum, nb);
    scan_final_kernel<<<nb, blk, 0, stream>>>(deg, bsum, rowptr, cursor, N, ET);
    scatter_phased<<<1024, blk, 0, stream>>>(ei, eflag, cursor, colv, E, ET, N, 1024);

    // ---- layer 1 aggregation (denom + weighted gather + relu/bias) ----
    agg_fused<1><<<ngrid4, blk, 0, stream>>>(rowptr, colv, ssrc, sdst, h, b1, nullptr, h1, N);

    // ---- layer 2 ----
    gemm_fused<128, false, 1, false><<<G1, blk, 0, stream>>>(
        h1, W2, h, N, a2s, a2d, ssrc, sdst, nullptr, nullptr, nullptr, nullptr, nullptr, 0, 0,
        N, G1);
    agg_fused<2><<<ngrid4, blk, 0, stream>>>(rowptr, colv, ssrc, sdst, h, b2, h1, o2, N);

    // ---- final linear with fused log_softmax ----
    gemm_fused<64, false, 2, false><<<G1, blk, 0, stream>>>(
        o2, Wl, nullptr, N, nullptr, nullptr, nullptr, nullptr, bl, out_logp, nullptr, nullptr,
        nullptr, 0, 0, N, G1);

    copy_ei_kernel<<<(2 * E + 255) / 256, blk, 0, stream>>>(ei, eflag, out_ei, 2 * E, N);
}

// Round 6
// 470.576 us; speedup vs baseline: 7.0592x; 1.0269x over previous
//
#include <hip/hip_runtime.h>

typedef unsigned short u16;
typedef __bf16 bf16x8 __attribute__((ext_vector_type(8)));
typedef float f32x4 __attribute__((ext_vector_type(4)));
typedef unsigned short u16x8 __attribute__((ext_vector_type(8)));

static __device__ __forceinline__ float bf2f(u16 u) {
    return __uint_as_float(((unsigned)u) << 16);
}
static __device__ __forceinline__ u16 f2bf(float f) {
    unsigned u = __float_as_uint(f);
    unsigned r = (u + 0x7FFFu + ((u >> 16) & 1u)) >> 16;
    return (u16)r;
}

// ---- edge_index word-stride detection: int32-packed (1) vs int64-as-2-words (2)
__global__ void detect_kernel(const int* __restrict__ ei, int* __restrict__ flag) {
    if (blockIdx.x == 0 && threadIdx.x == 0) {
        int zc = 0;
        for (int t = 0; t < 64; ++t) zc += (ei[2 * t + 1] == 0) ? 1 : 0;
        *flag = (zc >= 60) ? 2 : 1;
    }
}
static __device__ __forceinline__ int ld_idx(const int* ei, int pos, int st, int N) {
    int v = ei[(size_t)pos * (size_t)st];
    return v < 0 ? 0 : (v >= N ? N - 1 : v);
}

// ================= CSR scan (rowptr from deg) ================================
#define SCHUNK 4096
__global__ void scan_reduce_kernel(const int* __restrict__ deg, int* __restrict__ bsum, int N) {
    __shared__ int sdata[256];
    int t = threadIdx.x;
    int base = blockIdx.x * SCHUNK + t * 16;
    int s = 0;
#pragma unroll
    for (int j = 0; j < 16; ++j) { int i = base + j; s += (i < N) ? deg[i] : 0; }
    sdata[t] = s;
    __syncthreads();
    for (int o = 128; o > 0; o >>= 1) {
        if (t < o) sdata[t] += sdata[t + o];
        __syncthreads();
    }
    if (t == 0) bsum[blockIdx.x] = sdata[0];
}
__global__ void scan_mid_kernel(int* __restrict__ bsum, int nb) {
    if (threadIdx.x == 0 && blockIdx.x == 0) {
        int run = 0;
        for (int b = 0; b < nb; ++b) { int v = bsum[b]; bsum[b] = run; run += v; }
    }
}
__global__ void scan_final_kernel(const int* __restrict__ deg, const int* __restrict__ bsum,
                                  int* __restrict__ rowptr, int* __restrict__ cursor, int N,
                                  int ET) {
    __shared__ int sdata[256];
    int t = threadIdx.x;
    int base = blockIdx.x * SCHUNK + t * 16;
    int v[16];
    int s = 0;
#pragma unroll
    for (int j = 0; j < 16; ++j) {
        int i = base + j;
        v[j] = (i < N) ? deg[i] : 0;
        s += v[j];
    }
    sdata[t] = s;
    __syncthreads();
    for (int o = 1; o < 256; o <<= 1) {
        int add = (t >= o) ? sdata[t - o] : 0;
        __syncthreads();
        sdata[t] += add;
        __syncthreads();
    }
    int excl = (t == 0) ? 0 : sdata[t - 1];
    int off = bsum[blockIdx.x] + excl;
#pragma unroll
    for (int j = 0; j < 16; ++j) {
        int i = base + j;
        if (i < N) {
            rowptr[i] = off;
            cursor[i] = off;
            off += v[j];
        }
    }
    if (blockIdx.x == 0 && t == 0) rowptr[N] = ET;
}

// ---- XCD-sliced scatter: group x = blockIdx%8 exclusively owns dst slice x.
// The group's 128 WGs tile the full edge list; each edge is processed by exactly
// the group owning its dst. All writes to a given col/cursor line come from one
// group -> (with round-robin blockIdx->XCD) one XCD's L2 accumulates full lines.
__global__ __launch_bounds__(256) void scatter_xcd(const int* __restrict__ ei,
                                                   const int* __restrict__ flag,
                                                   int* __restrict__ cursor,
                                                   int* __restrict__ col, int E, int ET, int N,
                                                   int nwg) {
    const int st = *flag;
    const int x = blockIdx.x & 7;
    const int wgx = blockIdx.x >> 3;
    const int perx = nwg >> 3;
    const int Np = (N + 7) >> 3;
    const int lo = x * Np;
    const int hi = (lo + Np < N) ? lo + Np : N;
    const int stride = perx * 256;
    for (int j = wgx * 256 + (int)threadIdx.x; j < ET; j += stride) {
        int d = (j < E) ? ld_idx(ei, E + j, st, N) : (j - E);
        if (d >= lo && d < hi) {
            int s = (j < E) ? ld_idx(ei, j, st, N) : d;
            int pos = atomicAdd(&cursor[d], 1);
            col[pos] = s;
        }
    }
}

// ---------------- fused GEMM: C[M,NC] = A[M,128] @ W[128,NC]
// MFMA 16x16x32 bf16. A: A[m=lane&15][k=quad*8+j]; B: B[k=quad*8+j][n=lane&15];
// D: col=lane&15, row=quad*4+reg. W (f32) -> register-resident bf16 frags.
// EPI 1: store C bf16 + per-row scores (s_src,s_dst) via quad-lane reduction.
// EPI 2: no C store; fused log_softmax over NC=64 cols -> outp f32.
// HIST: blocks >= G1 instead histogram dst into deg (independent work, overlapped).
template <int NC, bool AF32, int EPI, bool HIST>
__global__ __launch_bounds__(256) void gemm_fused(
    const void* __restrict__ Ap, const float* __restrict__ W, u16* __restrict__ Cout, int M,
    const float* __restrict__ av_s, const float* __restrict__ av_d, float* __restrict__ ssrc,
    float* __restrict__ sdst, const float* __restrict__ bl, float* __restrict__ outp,
    const int* __restrict__ ei, const int* __restrict__ flag, int* __restrict__ deg, int E,
    int ET, int N, int G1) {
    if (HIST && (int)blockIdx.x >= G1) {
        int tid = ((int)blockIdx.x - G1) * 256 + threadIdx.x;
        int stride = ((int)gridDim.x - G1) * 256;
        int st = *flag;
        for (int j = tid; j < ET; j += stride) {
            int d = (j < E) ? ld_idx(ei, E + j, st, N) : j - E;
            atomicAdd(&deg[d], 1);
        }
        return;
    }
    const int lane = threadIdx.x & 63;
    const int quad = lane >> 4;
    const int r = lane & 15;
    const int gw = (blockIdx.x * 256 + threadIdx.x) >> 6;
    const int nw = G1 * 4;

    bf16x8 bf[NC / 16][4];
#pragma unroll
    for (int nt = 0; nt < NC / 16; ++nt)
#pragma unroll
        for (int kk = 0; kk < 4; ++kk) {
            union { bf16x8 v; u16 s[8]; } u;
#pragma unroll
            for (int j = 0; j < 8; ++j)
                u.s[j] = f2bf(W[(size_t)(kk * 32 + quad * 8 + j) * NC + nt * 16 + r]);
            bf[nt][kk] = u.v;
        }
    float avs[NC / 16], avd[NC / 16], blv[NC / 16];
    if (EPI == 1) {
#pragma unroll
        for (int nt = 0; nt < NC / 16; ++nt) {
            avs[nt] = av_s[nt * 16 + r];
            avd[nt] = av_d[nt * 16 + r];
        }
    }
    if (EPI == 2) {
#pragma unroll
        for (int nt = 0; nt < NC / 16; ++nt) blv[nt] = bl[nt * 16 + r];
    }

    const int ntiles = (M + 15) >> 4;
    for (int t = gw; t < ntiles; t += nw) {
        const int row0 = t << 4;
        bf16x8 af[4];
        if (AF32) {
            const float* arow = (const float*)Ap + (size_t)(row0 + r) * 128;
#pragma unroll
            for (int kk = 0; kk < 4; ++kk) {
                f32x4 f0 = *reinterpret_cast<const f32x4*>(arow + kk * 32 + quad * 8);
                f32x4 f1 = *reinterpret_cast<const f32x4*>(arow + kk * 32 + quad * 8 + 4);
                union { bf16x8 v; u16 s[8]; } u;
#pragma unroll
                for (int j = 0; j < 4; ++j) { u.s[j] = f2bf(f0[j]); u.s[4 + j] = f2bf(f1[j]); }
                af[kk] = u.v;
            }
        } else {
            const u16* arow = (const u16*)Ap + (size_t)(row0 + r) * 128;
#pragma unroll
            for (int kk = 0; kk < 4; ++kk)
                af[kk] = *reinterpret_cast<const bf16x8*>(arow + kk * 32 + quad * 8);
        }
        f32x4 acc[NC / 16];
#pragma unroll
        for (int nt = 0; nt < NC / 16; ++nt) acc[nt] = (f32x4){0.f, 0.f, 0.f, 0.f};
#pragma unroll
        for (int kk = 0; kk < 4; ++kk)
#pragma unroll
            for (int nt = 0; nt < NC / 16; ++nt)
                acc[nt] = __builtin_amdgcn_mfma_f32_16x16x32_bf16(af[kk], bf[nt][kk],
                                                                  acc[nt], 0, 0, 0);
        if (EPI != 2) {
#pragma unroll
            for (int nt = 0; nt < NC / 16; ++nt)
#pragma unroll
                for (int reg = 0; reg < 4; ++reg)
                    Cout[(size_t)(row0 + quad * 4 + reg) * NC + nt * 16 + r] =
                        f2bf(acc[nt][reg]);
        }
        if (EPI == 1) {
            float ps[4] = {0.f, 0.f, 0.f, 0.f}, pd[4] = {0.f, 0.f, 0.f, 0.f};
#pragma unroll
            for (int nt = 0; nt < NC / 16; ++nt)
#pragma unroll
                for (int reg = 0; reg < 4; ++reg) {
                    ps[reg] += acc[nt][reg] * avs[nt];
                    pd[reg] += acc[nt][reg] * avd[nt];
                }
#pragma unroll
            for (int o = 1; o < 16; o <<= 1)
#pragma unroll
                for (int reg = 0; reg < 4; ++reg) {
                    ps[reg] += __shfl_xor(ps[reg], o);
                    pd[reg] += __shfl_xor(pd[reg], o);
                }
            if (r == 0) {
#pragma unroll
                for (int reg = 0; reg < 4; ++reg) {
                    ssrc[row0 + quad * 4 + reg] = ps[reg];
                    sdst[row0 + quad * 4 + reg] = pd[reg];
                }
            }
        }
        if (EPI == 2) {
#pragma unroll
            for (int reg = 0; reg < 4; ++reg) {
                float v[NC / 16];
                float m = -3.4e38f;
#pragma unroll
                for (int nt = 0; nt < NC / 16; ++nt) {
                    v[nt] = acc[nt][reg] + blv[nt];
                    m = fmaxf(m, v[nt]);
                }
#pragma unroll
                for (int o = 1; o < 16; o <<= 1) m = fmaxf(m, __shfl_xor(m, o));
                float s = 0.f;
#pragma unroll
                for (int nt = 0; nt < NC / 16; ++nt) s += __expf(v[nt] - m);
#pragma unroll
                for (int o = 1; o < 16; o <<= 1) s += __shfl_xor(s, o);
                float L = __logf(s);
                const size_t rb = (size_t)(row0 + quad * 4 + reg) * NC;
#pragma unroll
                for (int nt = 0; nt < NC / 16; ++nt)
                    outp[rb + nt * 16 + r] = v[nt] - m - L;
            }
        }
    }
}

// ---------------- fused denom+agg over CSR: 16-lane group per dst node.
// pass A: denom = sum(exp(leaky(score))); pass B: weighted gather-accumulate.
// MODE 1: out = relu(acc + b).  MODE 2: out = acc + b + skip.
template <int MODE>
__global__ __launch_bounds__(256) void agg_fused(
    const int* __restrict__ rowptr, const int* __restrict__ col,
    const float* __restrict__ ssrc, const float* __restrict__ sdst,
    const u16* __restrict__ h, const float* __restrict__ b, const u16* __restrict__ skip,
    u16* __restrict__ out, int N) {
    const int lane = threadIdx.x & 63;
    const int gwave = (blockIdx.x * 256 + threadIdx.x) >> 6;
    const int grp = lane >> 4;
    const int ln = lane & 15;
    const int i = gwave * 4 + grp;
    if (i >= N) return;
    const int start = rowptr[i], end = rowptr[i + 1];
    const float sd = sdst[i];
    float sm = 0.f;
    for (int e = start + ln; e < end; e += 16) {
        float sc = ssrc[col[e]] + sd;
        sc = sc > 0.f ? sc : 0.2f * sc;
        sm += __expf(fminf(sc, 60.f));
    }
#pragma unroll
    for (int o = 1; o < 16; o <<= 1) sm += __shfl_xor(sm, o);
    const float rd = 1.f / sm;

    const size_t coff = (size_t)ln * 8;
    float acc[8] = {0.f, 0.f, 0.f, 0.f, 0.f, 0.f, 0.f, 0.f};
    int e = start;
    for (; e + 2 <= end; e += 2) {
        int c0 = col[e], c1 = col[e + 1];
        float s0 = ssrc[c0] + sd;
        float s1 = ssrc[c1] + sd;
        s0 = s0 > 0.f ? s0 : 0.2f * s0;
        s1 = s1 > 0.f ? s1 : 0.2f * s1;
        float w0 = __expf(fminf(s0, 60.f)) * rd;
        float w1 = __expf(fminf(s1, 60.f)) * rd;
        u16x8 r0 = *reinterpret_cast<const u16x8*>(h + (size_t)c0 * 128 + coff);
        u16x8 r1 = *reinterpret_cast<const u16x8*>(h + (size_t)c1 * 128 + coff);
#pragma unroll
        for (int j = 0; j < 8; ++j) acc[j] += w0 * bf2f(r0[j]) + w1 * bf2f(r1[j]);
    }
    if (e < end) {
        int c0 = col[e];
        float s0 = ssrc[c0] + sd;
        s0 = s0 > 0.f ? s0 : 0.2f * s0;
        float w0 = __expf(fminf(s0, 60.f)) * rd;
        u16x8 r0 = *reinterpret_cast<const u16x8*>(h + (size_t)c0 * 128 + coff);
#pragma unroll
        for (int j = 0; j < 8; ++j) acc[j] += w0 * bf2f(r0[j]);
    }
    u16x8 o;
    if (MODE == 1) {
#pragma unroll
        for (int j = 0; j < 8; ++j) {
            float v = acc[j] + b[coff + j];
            v = v > 0.f ? v : 0.f;
            o[j] = f2bf(v);
        }
    } else {
        const u16x8 sk = *reinterpret_cast<const u16x8*>(skip + (size_t)i * 128 + coff);
#pragma unroll
        for (int j = 0; j < 8; ++j) {
            float v = acc[j] + b[coff + j] + bf2f(sk[j]);
            o[j] = f2bf(v);
        }
    }
    *reinterpret_cast<u16x8*>(out + (size_t)i * 128 + coff) = o;
}

// ---------------- echo edge_index as f32 (output 1)
__global__ void copy_ei_kernel(const int* __restrict__ ei, const int* __restrict__ flag,
                               float* __restrict__ out, int n, int N) {
    int j = blockIdx.x * 256 + threadIdx.x;
    if (j < n) out[j] = (float)ld_idx(ei, j, *flag, N);
}

extern "C" void kernel_launch(void* const* d_in, const int* in_sizes, int n_in, void* d_out,
                              int out_size, void* d_ws, size_t ws_size, hipStream_t stream) {
    int ix = 0, iei = 1;
    if (in_sizes[0] < in_sizes[1]) { ix = 1; iei = 0; }
    const float* x = (const float*)d_in[ix];
    const int* ei = (const int*)d_in[iei];
    const float* W1 = (const float*)d_in[2];
    const float* a1s = (const float*)d_in[3];
    const float* a1d = (const float*)d_in[4];
    const float* b1 = (const float*)d_in[5];
    const float* W2 = (const float*)d_in[6];
    const float* a2s = (const float*)d_in[7];
    const float* a2d = (const float*)d_in[8];
    const float* b2 = (const float*)d_in[9];
    const float* Wl = (const float*)d_in[10];
    const float* bl = (const float*)d_in[11];

    const int N = in_sizes[ix] / 128;
    const int E = (out_size - N * 64) / 2;  // out = [logp N*64 | edge_index 2E], f32
    const int ET = E + N;

    char* ws = (char*)d_ws;
    size_t off = 0;
    auto alloc = [&](size_t bytes) {
        void* p = ws + off;
        off += (bytes + 255) & ~(size_t)255;
        return p;
    };
    u16* h = (u16*)alloc((size_t)N * 128 * 2);   // bf16 gemm out / gather source
    u16* h1 = (u16*)alloc((size_t)N * 128 * 2);  // bf16 layer-1 activation (skip input)
    u16* o2 = (u16*)alloc((size_t)N * 128 * 2);  // bf16 layer-2 out (final gemm input)
    float* ssrc = (float*)alloc((size_t)N * 4);
    float* sdst = (float*)alloc((size_t)N * 4);
    int* eflag = (int*)alloc(256);
    int* deg = (int*)alloc((size_t)N * 4);
    int* cursor = (int*)alloc((size_t)N * 4);
    int* rowptr = (int*)alloc((size_t)(N + 1) * 4);
    int* bsum = (int*)alloc(4096);
    int* colv = (int*)alloc((size_t)ET * 4);

    float* out_logp = (float*)d_out;
    float* out_ei = out_logp + (size_t)N * 64;

    dim3 blk(256);
    const int ngrid4 = (N + 15) / 16;  // 16-lane group per node, 16 nodes/block
    const int nb = (N + SCHUNK - 1) / SCHUNK;
    const int G1 = 512;  // gemm blocks in fused gemm+hist

    detect_kernel<<<1, 64, 0, stream>>>(ei, eflag);
    hipMemsetAsync(deg, 0, (size_t)N * 4, stream);

    // ---- layer-1 GEMM (+scores epilogue) fused with dst histogram ----
    gemm_fused<128, true, 1, true><<<G1 + 512, blk, 0, stream>>>(
        x, W1, h, N, a1s, a1d, ssrc, sdst, nullptr, nullptr, ei, eflag, deg, E, ET, N, G1);

    // ---- CSR scan + XCD-sliced scatter ----
    scan_reduce_kernel<<<nb, blk, 0, stream>>>(deg, bsum, N);
    scan_mid_kernel<<<1, 64, 0, stream>>>(bsum, nb);
    scan_final_kernel<<<nb, blk, 0, stream>>>(deg, bsum, rowptr, cursor, N, ET);
    scatter_xcd<<<1024, blk, 0, stream>>>(ei, eflag, cursor, colv, E, ET, N, 1024);

    // ---- layer 1 aggregation (denom + weighted gather + relu/bias) ----
    agg_fused<1><<<ngrid4, blk, 0, stream>>>(rowptr, colv, ssrc, sdst, h, b1, nullptr, h1, N);

    // ---- layer 2 ----
    gemm_fused<128, false, 1, false><<<G1, blk, 0, stream>>>(
        h1, W2, h, N, a2s, a2d, ssrc, sdst, nullptr, nullptr, nullptr, nullptr, nullptr, 0, 0,
        N, G1);
    agg_fused<2><<<ngrid4, blk, 0, stream>>>(rowptr, colv, ssrc, sdst, h, b2, h1, o2, N);

    // ---- final linear with fused log_softmax ----
    gemm_fused<64, false, 2, false><<<G1, blk, 0, stream>>>(
        o2, Wl, nullptr, N, nullptr, nullptr, nullptr, nullptr, bl, out_logp, nullptr, nullptr,
        nullptr, 0, 0, N, G1);

    copy_ei_kernel<<<(2 * E + 255) / 256, blk, 0, stream>>>(ei, eflag, out_ei, 2 * E, N);
}